// Round 8
// baseline (575.093 us; speedup 1.0000x reference)
//
#include <hip/hip_runtime.h>
#include <math.h>

#define SEQ 2048
#define HID 3584
#define NH 28
#define NKV 4
#define HD 128
#define GQA (NH / NKV)
#define NQKV (NH * HD + 2 * NKV * HD)  // 4608
#define NSLOT 60                       // (qtile, chunk) slots per head, QBLK=64, CHUNK=12 tiles
#define KS2 0.12752997f                // (1/sqrt(128)) * log2(e)
#define DTHR 90.50967f                 // 8 / (1/sqrt(128)) : defer-max threshold (raw domain)

typedef __attribute__((ext_vector_type(8))) short short8;
typedef __attribute__((ext_vector_type(4))) float f32x4;
typedef unsigned int u32;
typedef unsigned short ushort_t;

__device__ inline ushort_t f2bf(float f) {
  u32 x = __float_as_uint(f);
  return (ushort_t)((x + 0x7FFFu + ((x >> 16) & 1u)) >> 16);
}
__device__ inline float bf2f(ushort_t h) {
  return __uint_as_float(((u32)h) << 16);
}
__device__ inline void gload16(const void* g, void* l) {
  __builtin_amdgcn_global_load_lds((const u32 __attribute__((address_space(1)))*)g,
                                   (u32 __attribute__((address_space(3)))*)l, 16, 0, 0);
}

// ---------------- cast x -> bf16 ----------------
__global__ __launch_bounds__(256) void cast_bf16_kernel(const float* __restrict__ in,
                                                        ushort_t* __restrict__ out, int n4) {
  int i = blockIdx.x * blockDim.x + threadIdx.x;
  if (i >= n4) return;
  float4 v = ((const float4*)in)[i];
  ushort4 o;
  o.x = f2bf(v.x); o.y = f2bf(v.y); o.z = f2bf(v.z); o.w = f2bf(v.w);
  *(ushort4*)&out[(size_t)i * 4] = o;
}

// ---------------- transpose-cast: in [K][N] f32 -> out [N][K] bf16 ----------------
__global__ __launch_bounds__(256) void transpose_cast_kernel(const float* __restrict__ in,
                                                             ushort_t* __restrict__ out,
                                                             int K, int N) {
  __shared__ ushort_t t[64][65];
  const int bk = blockIdx.y * 64, bn = blockIdx.x * 64;
  const int tid = threadIdx.x;
#pragma unroll
  for (int i = 0; i < 4; i++) {
    int idx = i * 256 + tid;
    int r = idx >> 4, c4 = idx & 15;
    float4 v = *(const float4*)&in[(size_t)(bk + r) * N + bn + c4 * 4];
    t[c4 * 4 + 0][r] = f2bf(v.x);
    t[c4 * 4 + 1][r] = f2bf(v.y);
    t[c4 * 4 + 2][r] = f2bf(v.z);
    t[c4 * 4 + 3][r] = f2bf(v.w);
  }
  __syncthreads();
#pragma unroll
  for (int i = 0; i < 4; i++) {
    int idx = i * 256 + tid;
    int r = idx >> 4, c4 = idx & 15;
    ushort4 o;
    o.x = t[r][c4 * 4 + 0]; o.y = t[r][c4 * 4 + 1];
    o.z = t[r][c4 * 4 + 2]; o.w = t[r][c4 * 4 + 3];
    *(ushort4*)&out[(size_t)(bn + r) * K + bk + c4 * 4] = o;
  }
}

// ---------------- bf16 MFMA GEMM ----------------
// C[M][N] = A[M][K] @ BT[N][K]^T (+bias).
// mode 0: f32 out (Cf). mode 1: bf16 out (Cb).
// mode 3: fused QKV routing: cols [0,3584)->Cb (q), [3584,4096)->Ck (k),
//         [4096,4608)->Cv transposed (vT).
__global__ __launch_bounds__(256) void gemm_mfma(
    const ushort_t* __restrict__ A, const ushort_t* __restrict__ BT,
    const float* __restrict__ bias, float* __restrict__ Cf, ushort_t* __restrict__ Cb,
    ushort_t* __restrict__ Ck, ushort_t* __restrict__ Cv,
    const float* __restrict__ bias_k, const float* __restrict__ bias_v,
    int M, int N, int K, int mode) {
  __shared__ __align__(16) ushort_t As[2][128 * 32];
  __shared__ __align__(16) ushort_t Bs[2][128 * 32];
  const int tid = threadIdx.x;
  const int w = tid >> 6, lane = tid & 63;
  const int g = lane >> 4, r16 = lane & 15;
  const int wr = w >> 1, wc = w & 1;
  const int bm = blockIdx.y * 128, bn = blockIdx.x * 128;

  f32x4 acc[4][4];
#pragma unroll
  for (int i = 0; i < 4; i++)
#pragma unroll
    for (int j = 0; j < 4; j++) acc[i][j] = (f32x4){0.f, 0.f, 0.f, 0.f};

  const int nk = K >> 5;
#pragma unroll
  for (int i = 0; i < 2; i++) {
    int gi = i * 256 + w * 64 + lane;
    int row = gi >> 2, gc = gi & 3;
    gload16(&A[(size_t)(bm + row) * K + gc * 8], &As[0][(i * 256 + w * 64) * 8]);
    gload16(&BT[(size_t)(bn + row) * K + gc * 8], &Bs[0][(i * 256 + w * 64) * 8]);
  }
  __syncthreads();

  int buf = 0;
  for (int kt = 0; kt < nk; kt++) {
    if (kt + 1 < nk) {
      const int k0 = (kt + 1) << 5;
#pragma unroll
      for (int i = 0; i < 2; i++) {
        int gi = i * 256 + w * 64 + lane;
        int row = gi >> 2, gc = gi & 3;
        gload16(&A[(size_t)(bm + row) * K + k0 + gc * 8], &As[buf ^ 1][(i * 256 + w * 64) * 8]);
        gload16(&BT[(size_t)(bn + row) * K + k0 + gc * 8], &Bs[buf ^ 1][(i * 256 + w * 64) * 8]);
      }
    }
    short8 af[4], bfr[4];
#pragma unroll
    for (int mi = 0; mi < 4; mi++)
      af[mi] = *(const short8*)&As[buf][((wr * 64 + mi * 16 + r16) * 4 + g) * 8];
#pragma unroll
    for (int ni = 0; ni < 4; ni++)
      bfr[ni] = *(const short8*)&Bs[buf][((wc * 64 + ni * 16 + r16) * 4 + g) * 8];
    __builtin_amdgcn_s_setprio(1);
#pragma unroll
    for (int mi = 0; mi < 4; mi++)
#pragma unroll
      for (int ni = 0; ni < 4; ni++)
        acc[mi][ni] = __builtin_amdgcn_mfma_f32_16x16x32_bf16(af[mi], bfr[ni], acc[mi][ni], 0, 0, 0);
    __builtin_amdgcn_s_setprio(0);
    __syncthreads();
    buf ^= 1;
  }

  if (mode == 3) {
#pragma unroll
    for (int mi = 0; mi < 4; mi++)
#pragma unroll
      for (int ni = 0; ni < 4; ni++)
#pragma unroll
        for (int r = 0; r < 4; r++) {
          int row = bm + wr * 64 + mi * 16 + 4 * g + r;
          int col = bn + wc * 64 + ni * 16 + r16;
          float v = acc[mi][ni][r];
          if (bn < NH * HD) {
            Cb[(size_t)row * (NH * HD) + col] = f2bf(v + bias[col]);
          } else if (bn < NH * HD + NKV * HD) {
            int c = col - NH * HD;
            Ck[(size_t)row * (NKV * HD) + c] = f2bf(v + bias_k[c]);
          } else {
            int c = col - (NH * HD + NKV * HD);
            Cv[(size_t)c * M + row] = f2bf(v + bias_v[c]);
          }
        }
    return;
  }
#pragma unroll
  for (int mi = 0; mi < 4; mi++)
#pragma unroll
    for (int ni = 0; ni < 4; ni++)
#pragma unroll
      for (int r = 0; r < 4; r++) {
        int row = bm + wr * 64 + mi * 16 + 4 * g + r;
        int col = bn + wc * 64 + ni * 16 + r16;
        float v = acc[mi][ni][r];
        if (bias) v += bias[col];
        if (mode == 0) Cf[(size_t)row * N + col] = v;
        else Cb[(size_t)row * N + col] = f2bf(v);
      }
}

// ---------------- RoPE in-place on bf16 [S][nheads][128] ----------------
__global__ void rope_kernel(ushort_t* __restrict__ buf, const float* __restrict__ cosd,
                            const float* __restrict__ sind, int nheads) {
  const int s = blockIdx.x, h = blockIdx.y, d = threadIdx.x;  // d: 0..63
  const float c = cosd[s * 64 + d], sn = sind[s * 64 + d];
  ushort_t* p = buf + ((size_t)s * nheads + h) * HD;
  float x1 = bf2f(p[d]), x2 = bf2f(p[d + 64]);
  p[d] = f2bf(x1 * c - x2 * sn);
  p[d + 64] = f2bf(x1 * sn + x2 * c);
}

// ---------------- split-K MFMA causal GQA flash attention ----------------
// BARRIER-FREE: each wave independently processes 16 q-rows x one chunk of
// <=12 K-tiles. K and V fragments loaded straight from global (L2-resident:
// K/V per kv-head = 512 KB each). Only per-wave Ps lives in LDS (no barrier,
// lgkmcnt only). No __syncthreads in the whole kernel; waves free-run.
// Lane-local lrow; defer-max shuffle-free common path.
__global__ __launch_bounds__(256, 4) void attn_split(
    const ushort_t* __restrict__ q, const ushort_t* __restrict__ k,
    const ushort_t* __restrict__ vT, ushort_t* __restrict__ Opart,
    float* __restrict__ Mpart, float* __restrict__ Lpart) {
  const int b = (NSLOT - 1) - blockIdx.x;  // longest chunks dispatch first
  int qt, c;
  if (b < 12) { qt = b; c = 0; }
  else if (b < 36) { qt = 12 + (b - 12) / 2; c = (b - 12) & 1; }
  else { qt = 24 + (b - 36) / 3; c = (b - 36) % 3; }
  const int h = blockIdx.y, kvh = h / GQA;
  const int q0 = qt * 64;
  const int tstart = c * 12;
  const int tend = min(tstart + 12, qt + 1);
  const int tid = threadIdx.x, w = tid >> 6, lane = tid & 63;
  const int g = lane >> 4, r16 = lane & 15;

  __shared__ __align__(16) ushort_t Ps[4][16][72];  // per-wave P transpose buffer

  // Q fragment: rows q0 + w*16 + r16
  short8 qf[4];
  {
    const ushort_t* qp = q + (size_t)(q0 + w * 16 + r16) * (NH * HD) + h * HD;
#pragma unroll
    for (int f = 0; f < 4; f++) qf[f] = *(const short8*)(qp + f * 32 + g * 8);
  }
  float mrow[4], lrow[4];  // mrow row-uniform; lrow LANE-LOCAL partial
#pragma unroll
  for (int r = 0; r < 4; r++) { mrow[r] = -1e30f; lrow[r] = 0.f; }
  f32x4 oa[8];
#pragma unroll
  for (int d = 0; d < 8; d++) oa[d] = (f32x4){0.f, 0.f, 0.f, 0.f};

  const ushort_t* vbase = vT + (size_t)kvh * HD * SEQ;
  const ushort_t* kbase = k + (size_t)kvh * HD;

  for (int t = tstart; t < tend; t++) {
    const int kb = t * 64;

    // ---- QK^T: K fragments direct from global (L2), per-kb4 transient regs ----
    f32x4 sfr[4];
    __builtin_amdgcn_s_setprio(1);
#pragma unroll
    for (int kb4 = 0; kb4 < 4; kb4++) {
      const ushort_t* krow = kbase + (size_t)(kb + kb4 * 16 + r16) * (NKV * HD);
      short8 kf0 = *(const short8*)(krow + g * 8);
      short8 kf1 = *(const short8*)(krow + 32 + g * 8);
      short8 kf2 = *(const short8*)(krow + 64 + g * 8);
      short8 kf3 = *(const short8*)(krow + 96 + g * 8);
      f32x4 acc = (f32x4){0.f, 0.f, 0.f, 0.f};
      acc = __builtin_amdgcn_mfma_f32_16x16x32_bf16(qf[0], kf0, acc, 0, 0, 0);
      acc = __builtin_amdgcn_mfma_f32_16x16x32_bf16(qf[1], kf1, acc, 0, 0, 0);
      acc = __builtin_amdgcn_mfma_f32_16x16x32_bf16(qf[2], kf2, acc, 0, 0, 0);
      acc = __builtin_amdgcn_mfma_f32_16x16x32_bf16(qf[3], kf3, acc, 0, 0, 0);
      sfr[kb4] = acc;
    }
    __builtin_amdgcn_s_setprio(0);

    // ---- V first half preload (d=0..3): latency hides under softmax ----
    short8 vreg[8];
#pragma unroll
    for (int d = 0; d < 4; d++) {
      const ushort_t* vrow = vbase + (size_t)(d * 16 + r16) * SEQ + kb;
      vreg[2 * d]     = *(const short8*)(vrow + g * 8);
      vreg[2 * d + 1] = *(const short8*)(vrow + 32 + g * 8);
    }

    // causal mask: only final tile (t == qt) is partial
    if (t == qt) {
#pragma unroll
      for (int kb4 = 0; kb4 < 4; kb4++)
#pragma unroll
        for (int r = 0; r < 4; r++)
          if (kb4 * 16 + r16 > w * 16 + 4 * g + r) sfr[kb4][r] = -1e30f;
    }

    // ---- online softmax: shuffle-free common path (defer-max) ----
    float pm[4];
    bool need = false;
#pragma unroll
    for (int r = 0; r < 4; r++) {
      pm[r] = fmaxf(fmaxf(sfr[0][r], sfr[1][r]), fmaxf(sfr[2][r], sfr[3][r]));
      need |= (pm[r] > mrow[r] + DTHR);
    }
    if (__any(need)) {  // rare after first tile: full row-max reduce + rescale
#pragma unroll
      for (int r = 0; r < 4; r++) {
        float x = pm[r];
        x = fmaxf(x, __shfl_xor(x, 1));
        x = fmaxf(x, __shfl_xor(x, 2));
        x = fmaxf(x, __shfl_xor(x, 4));
        x = fmaxf(x, __shfl_xor(x, 8));
        float nm = fmaxf(mrow[r], x);
        float resc = exp2f((mrow[r] - nm) * KS2);
        mrow[r] = nm;
        lrow[r] *= resc;
#pragma unroll
        for (int d = 0; d < 8; d++) oa[d][r] *= resc;
      }
    }
#pragma unroll
    for (int kb4 = 0; kb4 < 4; kb4++)
#pragma unroll
      for (int r = 0; r < 4; r++) {
        float p = exp2f((sfr[kb4][r] - mrow[r]) * KS2);
        lrow[r] += p;  // lane-local partial sum
        Ps[w][4 * g + r][kb4 * 16 + r16] = f2bf(p);
      }

    // ---- PV: O[16][128] += P[16][64] @ V[64][128]; V in two register halves ----
    short8 pf0 = *(const short8*)&Ps[w][r16][g * 8];
    short8 pf1 = *(const short8*)&Ps[w][r16][32 + g * 8];
    __builtin_amdgcn_s_setprio(1);
#pragma unroll
    for (int d = 0; d < 4; d++) {
      oa[d] = __builtin_amdgcn_mfma_f32_16x16x32_bf16(pf0, vreg[2 * d], oa[d], 0, 0, 0);
      oa[d] = __builtin_amdgcn_mfma_f32_16x16x32_bf16(pf1, vreg[2 * d + 1], oa[d], 0, 0, 0);
    }
    __builtin_amdgcn_s_setprio(0);
    // second half loads (d=4..7) reuse vreg
#pragma unroll
    for (int d = 4; d < 8; d++) {
      const ushort_t* vrow = vbase + (size_t)(d * 16 + r16) * SEQ + kb;
      vreg[2 * (d - 4)]     = *(const short8*)(vrow + g * 8);
      vreg[2 * (d - 4) + 1] = *(const short8*)(vrow + 32 + g * 8);
    }
    __builtin_amdgcn_s_setprio(1);
#pragma unroll
    for (int d = 4; d < 8; d++) {
      oa[d] = __builtin_amdgcn_mfma_f32_16x16x32_bf16(pf0, vreg[2 * (d - 4)], oa[d], 0, 0, 0);
      oa[d] = __builtin_amdgcn_mfma_f32_16x16x32_bf16(pf1, vreg[2 * (d - 4) + 1], oa[d], 0, 0, 0);
    }
    __builtin_amdgcn_s_setprio(0);
  }

  // epilogue: reduce lane-local lrow once, write unnormalized partials
#pragma unroll
  for (int r = 0; r < 4; r++) {
    float s = lrow[r];
    s += __shfl_xor(s, 1); s += __shfl_xor(s, 2);
    s += __shfl_xor(s, 4); s += __shfl_xor(s, 8);
    lrow[r] = s;
  }
  const size_t slot = (size_t)h * NSLOT + b;
#pragma unroll
  for (int d = 0; d < 8; d++)
#pragma unroll
    for (int r = 0; r < 4; r++) {
      int lr = w * 16 + 4 * g + r;
      Opart[(slot * 64 + lr) * 128 + d * 16 + r16] = f2bf(oa[d][r]);
    }
  if (r16 == 0) {
#pragma unroll
    for (int r = 0; r < 4; r++) {
      int lr = w * 16 + 4 * g + r;
      Mpart[slot * 64 + lr] = mrow[r];
      Lpart[slot * 64 + lr] = lrow[r];
    }
  }
}

// ---------------- combine split-K partials ----------------
__global__ __launch_bounds__(128) void attn_reduce(
    const ushort_t* __restrict__ Opart, const float* __restrict__ Mpart,
    const float* __restrict__ Lpart, ushort_t* __restrict__ out) {
  const int s = blockIdx.x, h = blockIdx.y, d = threadIdx.x;
  const int qt = s >> 6;
  int b0, C;
  if (qt < 12) { b0 = qt; C = 1; }
  else if (qt < 24) { b0 = 12 + 2 * (qt - 12); C = 2; }
  else { b0 = 36 + 3 * (qt - 24); C = 3; }
  const int lr = s & 63;
  const size_t base = ((size_t)h * NSLOT + b0) * 64 + lr;
  float M = -1e30f;
  for (int c = 0; c < C; c++) M = fmaxf(M, Mpart[base + c * 64]);
  float L = 0.f, O = 0.f;
  for (int c = 0; c < C; c++) {
    float wgt = exp2f((Mpart[base + c * 64] - M) * KS2);
    L += wgt * Lpart[base + c * 64];
    O += wgt * bf2f(Opart[(base + c * 64) * 128 + d]);
  }
  out[(size_t)s * (NH * HD) + h * HD + d] = f2bf(O / L);
}

extern "C" void kernel_launch(void* const* d_in, const int* in_sizes, int n_in,
                              void* d_out, int out_size, void* d_ws, size_t ws_size,
                              hipStream_t stream) {
  const float* x    = (const float*)d_in[0];
  const float* wq   = (const float*)d_in[1];
  const float* bq   = (const float*)d_in[2];
  const float* wk   = (const float*)d_in[3];
  const float* bk   = (const float*)d_in[4];
  const float* wv   = (const float*)d_in[5];
  const float* bv   = (const float*)d_in[6];
  const float* wo   = (const float*)d_in[7];
  const float* cosd = (const float*)d_in[8];
  const float* sind = (const float*)d_in[9];
  float* out = (float*)d_out;

  ushort_t* ws   = (ushort_t*)d_ws;
  ushort_t* wT   = ws;                              // [4608][3584] qkv^T; later partials; later wo^T
  ushort_t* xb   = wT + (size_t)NQKV * HID;         // [2048][3584] (later attn out)
  ushort_t* qb   = xb + (size_t)SEQ * HID;          // [2048][3584]
  ushort_t* kb_  = qb + (size_t)SEQ * HID;          // [2048][512]
  ushort_t* vbT  = kb_ + (size_t)SEQ * (NKV * HD);  // [512][2048]
  ushort_t* aob  = xb;                              // reuse after QKV GEMM

  // split-K partials overlay the (dead after QKV GEMM) wT region:
  // 28*60*64*128*2B = 27.5MB + 2*28*60*64*4B = 0.86MB <= 33MB
  ushort_t* Opart = wT;                                            // [28][60][64][128] bf16
  float* Mpart = (float*)(wT + (size_t)NH * NSLOT * 64 * 128);     // [28][60][64]
  float* Lpart = Mpart + (size_t)NH * NSLOT * 64;                  // [28][60][64]

  // 1. cast x -> bf16
  cast_bf16_kernel<<<(SEQ * HID / 4) / 256, 256, 0, stream>>>(x, xb, SEQ * HID / 4);
  // 2. transpose-cast weights into fused [4608][3584]
  transpose_cast_kernel<<<dim3(HID / 64, HID / 64), 256, 0, stream>>>(wq, wT, HID, HID);
  transpose_cast_kernel<<<dim3((NKV * HD) / 64, HID / 64), 256, 0, stream>>>(
      wk, wT + (size_t)(NH * HD) * HID, HID, NKV * HD);
  transpose_cast_kernel<<<dim3((NKV * HD) / 64, HID / 64), 256, 0, stream>>>(
      wv, wT + (size_t)(NH * HD + NKV * HD) * HID, HID, NKV * HD);
  // 3. fused QKV projection
  gemm_mfma<<<dim3(NQKV / 128, SEQ / 128), 256, 0, stream>>>(
      xb, wT, bq, nullptr, qb, kb_, vbT, bk, bv, SEQ, NQKV, HID, 3);
  // 4. RoPE on q, k
  rope_kernel<<<dim3(SEQ, NH), 64, 0, stream>>>(qb, cosd, sind, NH);
  rope_kernel<<<dim3(SEQ, NKV), 64, 0, stream>>>(kb_, cosd, sind, NKV);
  // 5. split-K attention + reduce
  attn_split<<<dim3(NSLOT, NH), 256, 0, stream>>>(qb, kb_, vbT, Opart, Mpart, Lpart);
  attn_reduce<<<dim3(SEQ, NH), 128, 0, stream>>>(Opart, Mpart, Lpart, aob);
  // 6. output projection (reuse wT region for wo^T; partials dead after reduce)
  transpose_cast_kernel<<<dim3(HID / 64, HID / 64), 256, 0, stream>>>(wo, wT, HID, HID);
  gemm_mfma<<<dim3(HID / 128, SEQ / 128), 256, 0, stream>>>(
      aob, wT, nullptr, out, nullptr, nullptr, nullptr, nullptr, nullptr, SEQ, HID, HID, 0);
}

// Round 9
// 540.301 us; speedup vs baseline: 1.0644x; 1.0644x over previous
//
#include <hip/hip_runtime.h>
#include <math.h>

#define SEQ 2048
#define HID 3584
#define NH 28
#define NKV 4
#define HD 128
#define GQA (NH / NKV)
#define NQKV (NH * HD + 2 * NKV * HD)  // 4608
#define NSLOT 60                       // (qtile, chunk) slots per head, QBLK=64, CHUNK=12 tiles
#define KS2 0.12752997f                // (1/sqrt(128)) * log2(e)
#define DTHR 90.50967f                 // 8 / (1/sqrt(128)) : defer-max threshold (raw domain)

typedef __attribute__((ext_vector_type(8))) short short8;
typedef __attribute__((ext_vector_type(4))) float f32x4;
typedef unsigned int u32;
typedef unsigned short ushort_t;

__device__ inline ushort_t f2bf(float f) {
  u32 x = __float_as_uint(f);
  return (ushort_t)((x + 0x7FFFu + ((x >> 16) & 1u)) >> 16);
}
__device__ inline float bf2f(ushort_t h) {
  return __uint_as_float(((u32)h) << 16);
}
__device__ inline u32 pk2(float a, float b) {  // low=a, high=b
  return ((u32)f2bf(b) << 16) | (u32)f2bf(a);
}
__device__ inline void gload16(const void* g, void* l) {
  __builtin_amdgcn_global_load_lds((const u32 __attribute__((address_space(1)))*)g,
                                   (u32 __attribute__((address_space(3)))*)l, 16, 0, 0);
}

// ---------------- cast x -> bf16 ----------------
__global__ __launch_bounds__(256) void cast_bf16_kernel(const float* __restrict__ in,
                                                        ushort_t* __restrict__ out, int n4) {
  int i = blockIdx.x * blockDim.x + threadIdx.x;
  if (i >= n4) return;
  float4 v = ((const float4*)in)[i];
  ushort4 o;
  o.x = f2bf(v.x); o.y = f2bf(v.y); o.z = f2bf(v.z); o.w = f2bf(v.w);
  *(ushort4*)&out[(size_t)i * 4] = o;
}

// ---------------- transpose-cast: in [K][N] f32 -> out [N][K] bf16 ----------------
__global__ __launch_bounds__(256) void transpose_cast_kernel(const float* __restrict__ in,
                                                             ushort_t* __restrict__ out,
                                                             int K, int N) {
  __shared__ ushort_t t[64][65];
  const int bk = blockIdx.y * 64, bn = blockIdx.x * 64;
  const int tid = threadIdx.x;
#pragma unroll
  for (int i = 0; i < 4; i++) {
    int idx = i * 256 + tid;
    int r = idx >> 4, c4 = idx & 15;
    float4 v = *(const float4*)&in[(size_t)(bk + r) * N + bn + c4 * 4];
    t[c4 * 4 + 0][r] = f2bf(v.x);
    t[c4 * 4 + 1][r] = f2bf(v.y);
    t[c4 * 4 + 2][r] = f2bf(v.z);
    t[c4 * 4 + 3][r] = f2bf(v.w);
  }
  __syncthreads();
#pragma unroll
  for (int i = 0; i < 4; i++) {
    int idx = i * 256 + tid;
    int r = idx >> 4, c4 = idx & 15;
    ushort4 o;
    o.x = t[r][c4 * 4 + 0]; o.y = t[r][c4 * 4 + 1];
    o.z = t[r][c4 * 4 + 2]; o.w = t[r][c4 * 4 + 3];
    *(ushort4*)&out[(size_t)(bn + r) * K + bk + c4 * 4] = o;
  }
}

// ---------------- bf16 MFMA GEMM ----------------
__global__ __launch_bounds__(256) void gemm_mfma(
    const ushort_t* __restrict__ A, const ushort_t* __restrict__ BT,
    const float* __restrict__ bias, float* __restrict__ Cf, ushort_t* __restrict__ Cb,
    ushort_t* __restrict__ Ck, ushort_t* __restrict__ Cv,
    const float* __restrict__ bias_k, const float* __restrict__ bias_v,
    int M, int N, int K, int mode) {
  __shared__ __align__(16) ushort_t As[2][128 * 32];
  __shared__ __align__(16) ushort_t Bs[2][128 * 32];
  const int tid = threadIdx.x;
  const int w = tid >> 6, lane = tid & 63;
  const int g = lane >> 4, r16 = lane & 15;
  const int wr = w >> 1, wc = w & 1;
  const int bm = blockIdx.y * 128, bn = blockIdx.x * 128;

  f32x4 acc[4][4];
#pragma unroll
  for (int i = 0; i < 4; i++)
#pragma unroll
    for (int j = 0; j < 4; j++) acc[i][j] = (f32x4){0.f, 0.f, 0.f, 0.f};

  const int nk = K >> 5;
#pragma unroll
  for (int i = 0; i < 2; i++) {
    int gi = i * 256 + w * 64 + lane;
    int row = gi >> 2, gc = gi & 3;
    gload16(&A[(size_t)(bm + row) * K + gc * 8], &As[0][(i * 256 + w * 64) * 8]);
    gload16(&BT[(size_t)(bn + row) * K + gc * 8], &Bs[0][(i * 256 + w * 64) * 8]);
  }
  __syncthreads();

  int buf = 0;
  for (int kt = 0; kt < nk; kt++) {
    if (kt + 1 < nk) {
      const int k0 = (kt + 1) << 5;
#pragma unroll
      for (int i = 0; i < 2; i++) {
        int gi = i * 256 + w * 64 + lane;
        int row = gi >> 2, gc = gi & 3;
        gload16(&A[(size_t)(bm + row) * K + k0 + gc * 8], &As[buf ^ 1][(i * 256 + w * 64) * 8]);
        gload16(&BT[(size_t)(bn + row) * K + k0 + gc * 8], &Bs[buf ^ 1][(i * 256 + w * 64) * 8]);
      }
    }
    short8 af[4], bfr[4];
#pragma unroll
    for (int mi = 0; mi < 4; mi++)
      af[mi] = *(const short8*)&As[buf][((wr * 64 + mi * 16 + r16) * 4 + g) * 8];
#pragma unroll
    for (int ni = 0; ni < 4; ni++)
      bfr[ni] = *(const short8*)&Bs[buf][((wc * 64 + ni * 16 + r16) * 4 + g) * 8];
    __builtin_amdgcn_s_setprio(1);
#pragma unroll
    for (int mi = 0; mi < 4; mi++)
#pragma unroll
      for (int ni = 0; ni < 4; ni++)
        acc[mi][ni] = __builtin_amdgcn_mfma_f32_16x16x32_bf16(af[mi], bfr[ni], acc[mi][ni], 0, 0, 0);
    __builtin_amdgcn_s_setprio(0);
    __syncthreads();
    buf ^= 1;
  }

  if (mode == 3) {
#pragma unroll
    for (int mi = 0; mi < 4; mi++)
#pragma unroll
      for (int ni = 0; ni < 4; ni++)
#pragma unroll
        for (int r = 0; r < 4; r++) {
          int row = bm + wr * 64 + mi * 16 + 4 * g + r;
          int col = bn + wc * 64 + ni * 16 + r16;
          float v = acc[mi][ni][r];
          if (bn < NH * HD) {
            Cb[(size_t)row * (NH * HD) + col] = f2bf(v + bias[col]);
          } else if (bn < NH * HD + NKV * HD) {
            int c = col - NH * HD;
            Ck[(size_t)row * (NKV * HD) + c] = f2bf(v + bias_k[c]);
          } else {
            int c = col - (NH * HD + NKV * HD);
            Cv[(size_t)c * M + row] = f2bf(v + bias_v[c]);
          }
        }
    return;
  }
#pragma unroll
  for (int mi = 0; mi < 4; mi++)
#pragma unroll
    for (int ni = 0; ni < 4; ni++)
#pragma unroll
      for (int r = 0; r < 4; r++) {
        int row = bm + wr * 64 + mi * 16 + 4 * g + r;
        int col = bn + wc * 64 + ni * 16 + r16;
        float v = acc[mi][ni][r];
        if (bias) v += bias[col];
        if (mode == 0) Cf[(size_t)row * N + col] = v;
        else Cb[(size_t)row * N + col] = f2bf(v);
      }
}

// ---------------- RoPE in-place on bf16 [S][nheads][128] ----------------
__global__ void rope_kernel(ushort_t* __restrict__ buf, const float* __restrict__ cosd,
                            const float* __restrict__ sind, int nheads) {
  const int s = blockIdx.x, h = blockIdx.y, d = threadIdx.x;  // d: 0..63
  const float c = cosd[s * 64 + d], sn = sind[s * 64 + d];
  ushort_t* p = buf + ((size_t)s * nheads + h) * HD;
  float x1 = bf2f(p[d]), x2 = bf2f(p[d + 64]);
  p[d] = f2bf(x1 * c - x2 * sn);
  p[d + 64] = f2bf(x1 * sn + x2 * c);
}

// ---------------- split-K MFMA causal GQA flash attention ----------------
// BARRIER-FREE, LDS-FREE. Swapped-operand scheme:
//   S^T = mfma(K_rows, Q_rows): each lane holds 16 scores for ONE q-row (r16),
//   keys {16*kb4 + 4*g + r}. mrow/lrow are per-lane scalars.
//   P packed to bf16 in-register; fixed 4-group lane permutation (16 __shfl)
//   builds the B-fragment for O^T = mfma(V^T_rows, P^T): oa[dblk][r] =
//   O[q=r16][d=16*dblk+4*g+r] (4 contiguous d per lane -> ushort4 stores).
// K and V read straight from global (L2-resident). Waves fully independent.
__global__ __launch_bounds__(256) void attn_split(
    const ushort_t* __restrict__ q, const ushort_t* __restrict__ k,
    const ushort_t* __restrict__ vT, ushort_t* __restrict__ Opart,
    float* __restrict__ Mpart, float* __restrict__ Lpart) {
  const int b = (NSLOT - 1) - blockIdx.x;  // longest chunks dispatch first
  int qt, c;
  if (b < 12) { qt = b; c = 0; }
  else if (b < 36) { qt = 12 + (b - 12) / 2; c = (b - 12) & 1; }
  else { qt = 24 + (b - 36) / 3; c = (b - 36) % 3; }
  const int h = blockIdx.y, kvh = h / GQA;
  const int q0 = qt * 64;
  const int tstart = c * 12;
  const int tend = min(tstart + 12, qt + 1);
  const int tid = threadIdx.x, w = tid >> 6, lane = tid & 63;
  const int g = lane >> 4, r16 = lane & 15;

  // Q as B-fragment: q-row = r16 (per-lane column), k-chunks over d
  short8 qf[4];
  {
    const ushort_t* qp = q + (size_t)(q0 + w * 16 + r16) * (NH * HD) + h * HD;
#pragma unroll
    for (int f = 0; f < 4; f++) qf[f] = *(const short8*)(qp + f * 32 + g * 8);
  }
  float mrow = -1e30f, lrow = 0.f;  // per-lane scalars (lane's q-row = r16)
  f32x4 oa[8];
#pragma unroll
  for (int d = 0; d < 8; d++) oa[d] = (f32x4){0.f, 0.f, 0.f, 0.f};

  const ushort_t* vbase = vT + (size_t)kvh * HD * SEQ;
  const ushort_t* kbase = k + (size_t)kvh * HD;
  const int src0 = r16 + (((2 * g) & 3) << 4);
  const int src1 = r16 + (((2 * g + 1) & 3) << 4);
  const bool hi = (g >= 2);

  for (int t = tstart; t < tend; t++) {
    const int kb = t * 64;

    // ---- swapped QK^T: S^T[key][q] = mfma(K_rows, Q_rows) ----
    f32x4 sfr[4];
    __builtin_amdgcn_s_setprio(1);
#pragma unroll
    for (int kb4 = 0; kb4 < 4; kb4++) {
      const ushort_t* krow = kbase + (size_t)(kb + kb4 * 16 + r16) * (NKV * HD);
      short8 kf0 = *(const short8*)(krow + g * 8);
      short8 kf1 = *(const short8*)(krow + 32 + g * 8);
      short8 kf2 = *(const short8*)(krow + 64 + g * 8);
      short8 kf3 = *(const short8*)(krow + 96 + g * 8);
      f32x4 acc = (f32x4){0.f, 0.f, 0.f, 0.f};
      acc = __builtin_amdgcn_mfma_f32_16x16x32_bf16(kf0, qf[0], acc, 0, 0, 0);
      acc = __builtin_amdgcn_mfma_f32_16x16x32_bf16(kf1, qf[1], acc, 0, 0, 0);
      acc = __builtin_amdgcn_mfma_f32_16x16x32_bf16(kf2, qf[2], acc, 0, 0, 0);
      acc = __builtin_amdgcn_mfma_f32_16x16x32_bf16(kf3, qf[3], acc, 0, 0, 0);
      sfr[kb4] = acc;  // sfr[kb4][r] = S[q=r16][key=16*kb4+4*g+r] (raw)
    }
    __builtin_amdgcn_s_setprio(0);

    // causal mask: only final tile (t == qt) partial; kb == q0 there
    if (t == qt) {
      const int qrow = w * 16 + r16;
#pragma unroll
      for (int kb4 = 0; kb4 < 4; kb4++)
#pragma unroll
        for (int r = 0; r < 4; r++)
          if (kb4 * 16 + 4 * g + r > qrow) sfr[kb4][r] = -1e30f;
    }

    // ---- per-lane online softmax (defer-max) ----
    float pm = sfr[0][0];
#pragma unroll
    for (int kb4 = 0; kb4 < 4; kb4++)
#pragma unroll
      for (int r = 0; r < 4; r++) pm = fmaxf(pm, sfr[kb4][r]);
    if (__any(pm > mrow + DTHR)) {
      float x = pm;
      x = fmaxf(x, __shfl_xor(x, 16));
      x = fmaxf(x, __shfl_xor(x, 32));  // row-max across the 4 g-lanes
      float nm = fmaxf(mrow, x);
      float resc = exp2f((mrow - nm) * KS2);
      mrow = nm;
      lrow *= resc;
#pragma unroll
      for (int d = 0; d < 8; d++) {
        oa[d][0] *= resc; oa[d][1] *= resc; oa[d][2] *= resc; oa[d][3] *= resc;
      }
    }
    float p0[4], p1[4], p2[4], p3[4];
#pragma unroll
    for (int r = 0; r < 4; r++) {
      p0[r] = exp2f((sfr[0][r] - mrow) * KS2);
      p1[r] = exp2f((sfr[1][r] - mrow) * KS2);
      p2[r] = exp2f((sfr[2][r] - mrow) * KS2);
      p3[r] = exp2f((sfr[3][r] - mrow) * KS2);
      lrow += p0[r] + p1[r] + p2[r] + p3[r];
    }
    // pack: u[kb4][t] = keys (16*kb4 + 4*g + 2t, +1)
    u32 u0 = pk2(p0[0], p0[1]), u1 = pk2(p0[2], p0[3]);
    u32 u2 = pk2(p1[0], p1[1]), u3 = pk2(p1[2], p1[3]);
    u32 u4 = pk2(p2[0], p2[1]), u5 = pk2(p2[2], p2[3]);
    u32 u6 = pk2(p3[0], p3[1]), u7 = pk2(p3[2], p3[3]);
    // permutation: target lane g needs keys 8g..8g+7 (pf0) / 32+8g..+7 (pf1)
    u32 a, bb;
    union { u32 wd[4]; short8 v; } pf0u, pf1u;
    a = __shfl((int)u0, src0); bb = __shfl((int)u2, src0); pf0u.wd[0] = hi ? bb : a;
    a = __shfl((int)u1, src0); bb = __shfl((int)u3, src0); pf0u.wd[1] = hi ? bb : a;
    a = __shfl((int)u0, src1); bb = __shfl((int)u2, src1); pf0u.wd[2] = hi ? bb : a;
    a = __shfl((int)u1, src1); bb = __shfl((int)u3, src1); pf0u.wd[3] = hi ? bb : a;
    a = __shfl((int)u4, src0); bb = __shfl((int)u6, src0); pf1u.wd[0] = hi ? bb : a;
    a = __shfl((int)u5, src0); bb = __shfl((int)u7, src0); pf1u.wd[1] = hi ? bb : a;
    a = __shfl((int)u4, src1); bb = __shfl((int)u6, src1); pf1u.wd[2] = hi ? bb : a;
    a = __shfl((int)u5, src1); bb = __shfl((int)u7, src1); pf1u.wd[3] = hi ? bb : a;
    const short8 pf0 = pf0u.v, pf1 = pf1u.v;

    // ---- PV: O^T[d][q] += mfma(V^T_rows, P^T) ----
    __builtin_amdgcn_s_setprio(1);
#pragma unroll
    for (int d = 0; d < 8; d++) {
      const ushort_t* vrow = vbase + (size_t)(d * 16 + r16) * SEQ + kb;
      short8 vf0 = *(const short8*)(vrow + g * 8);
      short8 vf1 = *(const short8*)(vrow + 32 + g * 8);
      oa[d] = __builtin_amdgcn_mfma_f32_16x16x32_bf16(vf0, pf0, oa[d], 0, 0, 0);
      oa[d] = __builtin_amdgcn_mfma_f32_16x16x32_bf16(vf1, pf1, oa[d], 0, 0, 0);
    }
    __builtin_amdgcn_s_setprio(0);
  }

  // epilogue: reduce lrow across the 4 g-lanes; write partials
  {
    float s = lrow;
    s += __shfl_xor(s, 16);
    s += __shfl_xor(s, 32);
    lrow = s;
  }
  const size_t slot = (size_t)h * NSLOT + b;
  const int lr = w * 16 + r16;
#pragma unroll
  for (int d = 0; d < 8; d++) {
    ushort4 o4;
    o4.x = f2bf(oa[d][0]); o4.y = f2bf(oa[d][1]);
    o4.z = f2bf(oa[d][2]); o4.w = f2bf(oa[d][3]);
    *(ushort4*)&Opart[(slot * 64 + lr) * 128 + d * 16 + 4 * g] = o4;
  }
  if (g == 0) {
    Mpart[slot * 64 + lr] = mrow;
    Lpart[slot * 64 + lr] = lrow;
  }
}

// ---------------- combine split-K partials ----------------
__global__ __launch_bounds__(128) void attn_reduce(
    const ushort_t* __restrict__ Opart, const float* __restrict__ Mpart,
    const float* __restrict__ Lpart, ushort_t* __restrict__ out) {
  const int s = blockIdx.x, h = blockIdx.y, d = threadIdx.x;
  const int qt = s >> 6;
  int b0, C;
  if (qt < 12) { b0 = qt; C = 1; }
  else if (qt < 24) { b0 = 12 + 2 * (qt - 12); C = 2; }
  else { b0 = 36 + 3 * (qt - 24); C = 3; }
  const int lr = s & 63;
  const size_t base = ((size_t)h * NSLOT + b0) * 64 + lr;
  float M = -1e30f;
  for (int c = 0; c < C; c++) M = fmaxf(M, Mpart[base + c * 64]);
  float L = 0.f, O = 0.f;
  for (int c = 0; c < C; c++) {
    float wgt = exp2f((Mpart[base + c * 64] - M) * KS2);
    L += wgt * Lpart[base + c * 64];
    O += wgt * bf2f(Opart[(base + c * 64) * 128 + d]);
  }
  out[(size_t)s * (NH * HD) + h * HD + d] = f2bf(O / L);
}

extern "C" void kernel_launch(void* const* d_in, const int* in_sizes, int n_in,
                              void* d_out, int out_size, void* d_ws, size_t ws_size,
                              hipStream_t stream) {
  const float* x    = (const float*)d_in[0];
  const float* wq   = (const float*)d_in[1];
  const float* bq   = (const float*)d_in[2];
  const float* wk   = (const float*)d_in[3];
  const float* bk   = (const float*)d_in[4];
  const float* wv   = (const float*)d_in[5];
  const float* bv   = (const float*)d_in[6];
  const float* wo   = (const float*)d_in[7];
  const float* cosd = (const float*)d_in[8];
  const float* sind = (const float*)d_in[9];
  float* out = (float*)d_out;

  ushort_t* ws   = (ushort_t*)d_ws;
  ushort_t* wT   = ws;                              // [4608][3584] qkv^T; later partials; later wo^T
  ushort_t* xb   = wT + (size_t)NQKV * HID;         // [2048][3584] (later attn out)
  ushort_t* qb   = xb + (size_t)SEQ * HID;          // [2048][3584]
  ushort_t* kb_  = qb + (size_t)SEQ * HID;          // [2048][512]
  ushort_t* vbT  = kb_ + (size_t)SEQ * (NKV * HD);  // [512][2048]
  ushort_t* aob  = xb;                              // reuse after QKV GEMM

  // split-K partials overlay the (dead after QKV GEMM) wT region:
  // 28*60*64*128*2B = 27.5MB + 2*28*60*64*4B = 0.86MB <= 33MB
  ushort_t* Opart = wT;                                            // [28][60][64][128] bf16
  float* Mpart = (float*)(wT + (size_t)NH * NSLOT * 64 * 128);     // [28][60][64]
  float* Lpart = Mpart + (size_t)NH * NSLOT * 64;                  // [28][60][64]

  // 1. cast x -> bf16
  cast_bf16_kernel<<<(SEQ * HID / 4) / 256, 256, 0, stream>>>(x, xb, SEQ * HID / 4);
  // 2. transpose-cast weights into fused [4608][3584]
  transpose_cast_kernel<<<dim3(HID / 64, HID / 64), 256, 0, stream>>>(wq, wT, HID, HID);
  transpose_cast_kernel<<<dim3((NKV * HD) / 64, HID / 64), 256, 0, stream>>>(
      wk, wT + (size_t)(NH * HD) * HID, HID, NKV * HD);
  transpose_cast_kernel<<<dim3((NKV * HD) / 64, HID / 64), 256, 0, stream>>>(
      wv, wT + (size_t)(NH * HD + NKV * HD) * HID, HID, NKV * HD);
  // 3. fused QKV projection
  gemm_mfma<<<dim3(NQKV / 128, SEQ / 128), 256, 0, stream>>>(
      xb, wT, bq, nullptr, qb, kb_, vbT, bk, bv, SEQ, NQKV, HID, 3);
  // 4. RoPE on q, k
  rope_kernel<<<dim3(SEQ, NH), 64, 0, stream>>>(qb, cosd, sind, NH);
  rope_kernel<<<dim3(SEQ, NKV), 64, 0, stream>>>(kb_, cosd, sind, NKV);
  // 5. split-K attention + reduce
  attn_split<<<dim3(NSLOT, NH), 256, 0, stream>>>(qb, kb_, vbT, Opart, Mpart, Lpart);
  attn_reduce<<<dim3(SEQ, NH), 128, 0, stream>>>(Opart, Mpart, Lpart, aob);
  // 6. output projection (reuse wT region for wo^T; partials dead after reduce)
  transpose_cast_kernel<<<dim3(HID / 64, HID / 64), 256, 0, stream>>>(wo, wT, HID, HID);
  gemm_mfma<<<dim3(HID / 128, SEQ / 128), 256, 0, stream>>>(
      aob, wT, nullptr, out, nullptr, nullptr, nullptr, nullptr, nullptr, SEQ, HID, HID, 0);
}

// Round 10
// 426.691 us; speedup vs baseline: 1.3478x; 1.2663x over previous
//
#include <hip/hip_runtime.h>
#include <math.h>

#define SEQ 2048
#define HID 3584
#define NH 28
#define NKV 4
#define HD 128
#define GQA (NH / NKV)
#define NQKV (NH * HD + 2 * NKV * HD)  // 4608
#define NSLOT 30                       // slots/head: qt0-5 x1, qt6-11 x2, qt12-15 x3 (QBLK=128)
#define KS2 0.12752997f                // (1/sqrt(128)) * log2(e)
#define DTHR 90.50967f                 // 8 / (1/sqrt(128)) : defer-max threshold (raw domain)

typedef __attribute__((ext_vector_type(8))) short short8;
typedef __attribute__((ext_vector_type(4))) float f32x4;
typedef __attribute__((ext_vector_type(16))) float f32x16;
typedef unsigned int u32;
typedef unsigned short ushort_t;

__device__ inline ushort_t f2bf(float f) {
  u32 x = __float_as_uint(f);
  return (ushort_t)((x + 0x7FFFu + ((x >> 16) & 1u)) >> 16);
}
__device__ inline float bf2f(ushort_t h) {
  return __uint_as_float(((u32)h) << 16);
}
__device__ inline u32 pk2(float a, float b) {  // low=a, high=b
  return ((u32)f2bf(b) << 16) | (u32)f2bf(a);
}
__device__ inline void gload16(const void* g, void* l) {
  __builtin_amdgcn_global_load_lds((const u32 __attribute__((address_space(1)))*)g,
                                   (u32 __attribute__((address_space(3)))*)l, 16, 0, 0);
}

// ---------------- cast x -> bf16 ----------------
__global__ __launch_bounds__(256) void cast_bf16_kernel(const float* __restrict__ in,
                                                        ushort_t* __restrict__ out, int n4) {
  int i = blockIdx.x * blockDim.x + threadIdx.x;
  if (i >= n4) return;
  float4 v = ((const float4*)in)[i];
  ushort4 o;
  o.x = f2bf(v.x); o.y = f2bf(v.y); o.z = f2bf(v.z); o.w = f2bf(v.w);
  *(ushort4*)&out[(size_t)i * 4] = o;
}

// ---------------- transpose-cast: in [K][N] f32 -> out [N][K] bf16 ----------------
__global__ __launch_bounds__(256) void transpose_cast_kernel(const float* __restrict__ in,
                                                             ushort_t* __restrict__ out,
                                                             int K, int N) {
  __shared__ ushort_t t[64][65];
  const int bk = blockIdx.y * 64, bn = blockIdx.x * 64;
  const int tid = threadIdx.x;
#pragma unroll
  for (int i = 0; i < 4; i++) {
    int idx = i * 256 + tid;
    int r = idx >> 4, c4 = idx & 15;
    float4 v = *(const float4*)&in[(size_t)(bk + r) * N + bn + c4 * 4];
    t[c4 * 4 + 0][r] = f2bf(v.x);
    t[c4 * 4 + 1][r] = f2bf(v.y);
    t[c4 * 4 + 2][r] = f2bf(v.z);
    t[c4 * 4 + 3][r] = f2bf(v.w);
  }
  __syncthreads();
#pragma unroll
  for (int i = 0; i < 4; i++) {
    int idx = i * 256 + tid;
    int r = idx >> 4, c4 = idx & 15;
    ushort4 o;
    o.x = t[r][c4 * 4 + 0]; o.y = t[r][c4 * 4 + 1];
    o.z = t[r][c4 * 4 + 2]; o.w = t[r][c4 * 4 + 3];
    *(ushort4*)&out[(size_t)(bn + r) * K + bk + c4 * 4] = o;
  }
}

// ---------------- bf16 MFMA GEMM ----------------
__global__ __launch_bounds__(256) void gemm_mfma(
    const ushort_t* __restrict__ A, const ushort_t* __restrict__ BT,
    const float* __restrict__ bias, float* __restrict__ Cf, ushort_t* __restrict__ Cb,
    ushort_t* __restrict__ Ck, ushort_t* __restrict__ Cv,
    const float* __restrict__ bias_k, const float* __restrict__ bias_v,
    int M, int N, int K, int mode) {
  __shared__ __align__(16) ushort_t As[2][128 * 32];
  __shared__ __align__(16) ushort_t Bs[2][128 * 32];
  const int tid = threadIdx.x;
  const int w = tid >> 6, lane = tid & 63;
  const int g = lane >> 4, r16 = lane & 15;
  const int wr = w >> 1, wc = w & 1;
  const int bm = blockIdx.y * 128, bn = blockIdx.x * 128;

  f32x4 acc[4][4];
#pragma unroll
  for (int i = 0; i < 4; i++)
#pragma unroll
    for (int j = 0; j < 4; j++) acc[i][j] = (f32x4){0.f, 0.f, 0.f, 0.f};

  const int nk = K >> 5;
#pragma unroll
  for (int i = 0; i < 2; i++) {
    int gi = i * 256 + w * 64 + lane;
    int row = gi >> 2, gc = gi & 3;
    gload16(&A[(size_t)(bm + row) * K + gc * 8], &As[0][(i * 256 + w * 64) * 8]);
    gload16(&BT[(size_t)(bn + row) * K + gc * 8], &Bs[0][(i * 256 + w * 64) * 8]);
  }
  __syncthreads();

  int buf = 0;
  for (int kt = 0; kt < nk; kt++) {
    if (kt + 1 < nk) {
      const int k0 = (kt + 1) << 5;
#pragma unroll
      for (int i = 0; i < 2; i++) {
        int gi = i * 256 + w * 64 + lane;
        int row = gi >> 2, gc = gi & 3;
        gload16(&A[(size_t)(bm + row) * K + k0 + gc * 8], &As[buf ^ 1][(i * 256 + w * 64) * 8]);
        gload16(&BT[(size_t)(bn + row) * K + k0 + gc * 8], &Bs[buf ^ 1][(i * 256 + w * 64) * 8]);
      }
    }
    short8 af[4], bfr[4];
#pragma unroll
    for (int mi = 0; mi < 4; mi++)
      af[mi] = *(const short8*)&As[buf][((wr * 64 + mi * 16 + r16) * 4 + g) * 8];
#pragma unroll
    for (int ni = 0; ni < 4; ni++)
      bfr[ni] = *(const short8*)&Bs[buf][((wc * 64 + ni * 16 + r16) * 4 + g) * 8];
    __builtin_amdgcn_s_setprio(1);
#pragma unroll
    for (int mi = 0; mi < 4; mi++)
#pragma unroll
      for (int ni = 0; ni < 4; ni++)
        acc[mi][ni] = __builtin_amdgcn_mfma_f32_16x16x32_bf16(af[mi], bfr[ni], acc[mi][ni], 0, 0, 0);
    __builtin_amdgcn_s_setprio(0);
    __syncthreads();
    buf ^= 1;
  }

  if (mode == 3) {
#pragma unroll
    for (int mi = 0; mi < 4; mi++)
#pragma unroll
      for (int ni = 0; ni < 4; ni++)
#pragma unroll
        for (int r = 0; r < 4; r++) {
          int row = bm + wr * 64 + mi * 16 + 4 * g + r;
          int col = bn + wc * 64 + ni * 16 + r16;
          float v = acc[mi][ni][r];
          if (bn < NH * HD) {
            Cb[(size_t)row * (NH * HD) + col] = f2bf(v + bias[col]);
          } else if (bn < NH * HD + NKV * HD) {
            int c = col - NH * HD;
            Ck[(size_t)row * (NKV * HD) + c] = f2bf(v + bias_k[c]);
          } else {
            int c = col - (NH * HD + NKV * HD);
            Cv[(size_t)c * M + row] = f2bf(v + bias_v[c]);
          }
        }
    return;
  }
#pragma unroll
  for (int mi = 0; mi < 4; mi++)
#pragma unroll
    for (int ni = 0; ni < 4; ni++)
#pragma unroll
      for (int r = 0; r < 4; r++) {
        int row = bm + wr * 64 + mi * 16 + 4 * g + r;
        int col = bn + wc * 64 + ni * 16 + r16;
        float v = acc[mi][ni][r];
        if (bias) v += bias[col];
        if (mode == 0) Cf[(size_t)row * N + col] = v;
        else Cb[(size_t)row * N + col] = f2bf(v);
      }
}

// ---------------- RoPE in-place on bf16 [S][nheads][128] ----------------
__global__ void rope_kernel(ushort_t* __restrict__ buf, const float* __restrict__ cosd,
                            const float* __restrict__ sind, int nheads) {
  const int s = blockIdx.x, h = blockIdx.y, d = threadIdx.x;  // d: 0..63
  const float c = cosd[s * 64 + d], sn = sind[s * 64 + d];
  ushort_t* p = buf + ((size_t)s * nheads + h) * HD;
  float x1 = bf2f(p[d]), x2 = bf2f(p[d + 64]);
  p[d] = f2bf(x1 * c - x2 * sn);
  p[d + 64] = f2bf(x1 * sn + x2 * c);
}

// ---------------- split-K 32x32 swapped-operand causal GQA flash attention ----
// Block: 4 waves x 32 q-rows (QBLK=128) x chunk of <=12 KV-tiles (64 keys).
// QK^T = mfma_32x32x16(K, Q): lane holds 32 scores of q-row (lane&31),
//   key = kb + 32*st + (r&3)+8*(r>>2)+4*hi. Softmax per-lane scalar (defer-max).
// P packed to bf16 in-register; A-frags built with shfl_xor(32).
// PV = mfma_32x32x16(P, V): oa[dblk] reg r = O[q=crow(r,hi)][d=dblk*32+(lane&31)].
// K staged in LDS (dbuf, key&15 granule swizzle); V short8 direct from vT (L2).
__global__ __launch_bounds__(256) void attn_split(
    const ushort_t* __restrict__ q, const ushort_t* __restrict__ k,
    const ushort_t* __restrict__ vT, ushort_t* __restrict__ Opart,
    float* __restrict__ Mpart, float* __restrict__ Lpart) {
  const int b = (NSLOT - 1) - blockIdx.x;  // longer chunks dispatch first
  int qt, c;
  if (b < 6) { qt = b; c = 0; }
  else if (b < 18) { qt = 6 + (b - 6) / 2; c = (b - 6) & 1; }
  else { qt = 12 + (b - 18) / 3; c = (b - 18) % 3; }
  const int h = blockIdx.y, kvh = h / GQA;
  const int q0 = qt * 128;
  const int tstart = c * 12;
  const int tend = min(tstart + 12, 2 * qt + 2);
  const int tid = threadIdx.x, w = tid >> 6, lane = tid & 63;
  const int l31 = lane & 31, hi = lane >> 5;

  __shared__ __align__(16) ushort_t Ks[2][64 * 128];  // [key][d], granule ^= key&15

  // Q as B-fragment: q-row = q0 + w*32 + l31; frag f covers k = 16f + 8*hi + 0..7
  short8 qf[8];
  {
    const ushort_t* qp = q + (size_t)(q0 + w * 32 + l31) * (NH * HD) + h * HD + 8 * hi;
#pragma unroll
    for (int f = 0; f < 8; f++) qf[f] = *(const short8*)(qp + 16 * f);
  }
  float mrow = -1e30f, lrow = 0.f;  // per-lane; q-row = l31 (partner lane^32 same row)
  f32x16 oa[4];
#pragma unroll
  for (int d = 0; d < 4; d++)
#pragma unroll
    for (int e = 0; e < 16; e++) oa[d][e] = 0.f;

  const ushort_t* vbase = vT + (size_t)kvh * HD * SEQ;

#define STAGE(BUF, T)                                                                   \
  do {                                                                                  \
    const int kb_ = (T) * 64;                                                           \
    _Pragma("unroll") for (int i = 0; i < 4; i++) {                                     \
      int gi = i * 256 + tid;                                                           \
      int key = gi >> 4, gd = gi & 15;                                                  \
      int gsrc = gd ^ (key & 15);                                                       \
      gload16(&k[(size_t)(kb_ + key) * (NKV * HD) + kvh * HD + gsrc * 8],               \
              &Ks[BUF][gi * 8]);                                                        \
    }                                                                                   \
  } while (0)

  STAGE(0, tstart);
  __syncthreads();

  for (int t = tstart; t < tend; t++) {
    const int cur = (t - tstart) & 1;
    const int kb = t * 64;
    if (t + 1 < tend) STAGE(cur ^ 1, t + 1);  // prefetch next K tile

    const int qwave = q0 + w * 32;
    if (kb <= qwave + 31) {  // else: fully masked for this wave, skip compute
      // ---- QK^T: lane -> 32 scores of q-row l31 ----
      f32x16 sfr[2];
      __builtin_amdgcn_s_setprio(1);
#pragma unroll
      for (int st = 0; st < 2; st++) {
        f32x16 acc;
#pragma unroll
        for (int e = 0; e < 16; e++) acc[e] = 0.f;
        const int key = st * 32 + l31;
#pragma unroll
        for (int f = 0; f < 8; f++) {
          short8 kf = *(const short8*)&Ks[cur][(key * 16 + ((2 * f + hi) ^ (key & 15))) * 8];
          acc = __builtin_amdgcn_mfma_f32_32x32x16_bf16(kf, qf[f], acc, 0, 0, 0);
        }
        sfr[st] = acc;
      }
      __builtin_amdgcn_s_setprio(0);

      // ---- causal mask (raw scores) ----
      const int qg = q0 + w * 32 + l31;
      if (kb + 63 > qwave) {
#pragma unroll
        for (int st = 0; st < 2; st++)
#pragma unroll
          for (int e = 0; e < 16; e++) {
            int keyg = kb + st * 32 + (e & 3) + 8 * (e >> 2) + 4 * hi;
            if (keyg > qg) sfr[st][e] = -1e30f;
          }
      }

      // ---- per-lane online softmax (defer-max) ----
      float pm = -1e30f;
#pragma unroll
      for (int st = 0; st < 2; st++)
#pragma unroll
        for (int e = 0; e < 16; e++) pm = fmaxf(pm, sfr[st][e]);
      if (__any(pm > mrow + DTHR)) {
        float xm = fmaxf(pm, __shfl_xor(pm, 32));
        float nm = fmaxf(mrow, xm);
        float resc = exp2f((mrow - nm) * KS2);
        mrow = nm;
        lrow *= resc;
        // oa reg r belongs to q-row crow(r,hi); fetch that row's resc via shfl
        float rr[16];
#pragma unroll
        for (int r = 0; r < 16; r++) {
          int srcl = (r & 3) + 8 * (r >> 2) + 4 * hi;
          rr[r] = __shfl(resc, srcl);
        }
#pragma unroll
        for (int d = 0; d < 4; d++)
#pragma unroll
          for (int r = 0; r < 16; r++) oa[d][r] *= rr[r];
      }

      // ---- P = exp2, pack to bf16, accumulate lrow ----
      u32 pk[2][8];
      float psum = 0.f;
#pragma unroll
      for (int st = 0; st < 2; st++)
#pragma unroll
        for (int j = 0; j < 8; j++) {
          float pa = exp2f((sfr[st][2 * j] - mrow) * KS2);
          float pb = exp2f((sfr[st][2 * j + 1] - mrow) * KS2);
          psum += pa + pb;
          pk[st][j] = pk2(pa, pb);
        }
      lrow += psum;

      // ---- build P A-frags via shfl_xor(32): paf[ks], keys 16ks+8hi+0..7 ----
      short8 paf[4];
#pragma unroll
      for (int st = 0; st < 2; st++) {
        u32 x0 = (u32)__shfl_xor((int)pk[st][0], 32);
        u32 x1 = (u32)__shfl_xor((int)pk[st][1], 32);
        u32 x2 = (u32)__shfl_xor((int)pk[st][2], 32);
        u32 x3 = (u32)__shfl_xor((int)pk[st][3], 32);
        u32 x4 = (u32)__shfl_xor((int)pk[st][4], 32);
        u32 x5 = (u32)__shfl_xor((int)pk[st][5], 32);
        u32 x6 = (u32)__shfl_xor((int)pk[st][6], 32);
        u32 x7 = (u32)__shfl_xor((int)pk[st][7], 32);
        union { u32 wd[4]; short8 v; } fe, fo;
        if (hi == 0) {
          fe.wd[0] = pk[st][0]; fe.wd[1] = pk[st][1]; fe.wd[2] = x0; fe.wd[3] = x1;
          fo.wd[0] = pk[st][4]; fo.wd[1] = pk[st][5]; fo.wd[2] = x4; fo.wd[3] = x5;
        } else {
          fe.wd[0] = x2; fe.wd[1] = x3; fe.wd[2] = pk[st][2]; fe.wd[3] = pk[st][3];
          fo.wd[0] = x6; fo.wd[1] = x7; fo.wd[2] = pk[st][6]; fo.wd[3] = pk[st][7];
        }
        paf[2 * st] = fe.v;
        paf[2 * st + 1] = fo.v;
      }

      // ---- PV: oa[dblk] += P @ V, V from vT rows (L2), 2 dblk batches ----
#pragma unroll
      for (int half = 0; half < 2; half++) {
        short8 vf[8];
#pragma unroll
        for (int db = 0; db < 2; db++)
#pragma unroll
          for (int ks = 0; ks < 4; ks++)
            vf[db * 4 + ks] = *(const short8*)(vbase +
                (size_t)((half * 2 + db) * 32 + l31) * SEQ + kb + ks * 16 + 8 * hi);
        __builtin_amdgcn_s_setprio(1);
#pragma unroll
        for (int db = 0; db < 2; db++)
#pragma unroll
          for (int ks = 0; ks < 4; ks++)
            oa[half * 2 + db] = __builtin_amdgcn_mfma_f32_32x32x16_bf16(
                paf[ks], vf[db * 4 + ks], oa[half * 2 + db], 0, 0, 0);
        __builtin_amdgcn_s_setprio(0);
      }
    }
    __syncthreads();  // K prefetch landed + all waves done with Ks[cur]
  }
#undef STAGE

  // ---- epilogue ----
  lrow += __shfl_xor(lrow, 32);
  const size_t slot = (size_t)h * NSLOT + b;
#pragma unroll
  for (int d = 0; d < 4; d++)
#pragma unroll
    for (int r = 0; r < 16; r++) {
      int qloc = w * 32 + (r & 3) + 8 * (r >> 2) + 4 * hi;
      Opart[(slot * 128 + qloc) * 128 + d * 32 + l31] = f2bf(oa[d][r]);
    }
  if (hi == 0) {
    Mpart[slot * 128 + w * 32 + l31] = mrow;
    Lpart[slot * 128 + w * 32 + l31] = lrow;
  }
}

// ---------------- combine split-K partials ----------------
__global__ __launch_bounds__(128) void attn_reduce(
    const ushort_t* __restrict__ Opart, const float* __restrict__ Mpart,
    const float* __restrict__ Lpart, ushort_t* __restrict__ out) {
  const int s = blockIdx.x, h = blockIdx.y, d = threadIdx.x;
  const int qt = s >> 7;
  int b0, C;
  if (qt < 6) { b0 = qt; C = 1; }
  else if (qt < 12) { b0 = 6 + 2 * (qt - 6); C = 2; }
  else { b0 = 18 + 3 * (qt - 12); C = 3; }
  const int lr = s & 127;
  const size_t base = ((size_t)h * NSLOT + b0) * 128 + lr;
  float M = -1e30f;
  for (int c = 0; c < C; c++) M = fmaxf(M, Mpart[base + c * 128]);
  float L = 0.f, O = 0.f;
  for (int c = 0; c < C; c++) {
    float wgt = exp2f((Mpart[base + c * 128] - M) * KS2);
    L += wgt * Lpart[base + c * 128];
    O += wgt * bf2f(Opart[(base + c * 128) * 128 + d]);
  }
  out[(size_t)s * (NH * HD) + h * HD + d] = f2bf(O / L);
}

extern "C" void kernel_launch(void* const* d_in, const int* in_sizes, int n_in,
                              void* d_out, int out_size, void* d_ws, size_t ws_size,
                              hipStream_t stream) {
  const float* x    = (const float*)d_in[0];
  const float* wq   = (const float*)d_in[1];
  const float* bq   = (const float*)d_in[2];
  const float* wk   = (const float*)d_in[3];
  const float* bk   = (const float*)d_in[4];
  const float* wv   = (const float*)d_in[5];
  const float* bv   = (const float*)d_in[6];
  const float* wo   = (const float*)d_in[7];
  const float* cosd = (const float*)d_in[8];
  const float* sind = (const float*)d_in[9];
  float* out = (float*)d_out;

  ushort_t* ws   = (ushort_t*)d_ws;
  ushort_t* wT   = ws;                              // [4608][3584] qkv^T; later partials; later wo^T
  ushort_t* xb   = wT + (size_t)NQKV * HID;         // [2048][3584] (later attn out)
  ushort_t* qb   = xb + (size_t)SEQ * HID;          // [2048][3584]
  ushort_t* kb_  = qb + (size_t)SEQ * HID;          // [2048][512]
  ushort_t* vbT  = kb_ + (size_t)SEQ * (NKV * HD);  // [512][2048]
  ushort_t* aob  = xb;                              // reuse after QKV GEMM

  // split-K partials overlay the (dead after QKV GEMM) wT region:
  // 28*30*128*128*2B = 27.5MB + 2*28*30*128*4B = 0.86MB <= 33MB
  ushort_t* Opart = wT;                                            // [28][30][128][128] bf16
  float* Mpart = (float*)(wT + (size_t)NH * NSLOT * 128 * 128);    // [28][30][128]
  float* Lpart = Mpart + (size_t)NH * NSLOT * 128;                 // [28][30][128]

  // 1. cast x -> bf16
  cast_bf16_kernel<<<(SEQ * HID / 4) / 256, 256, 0, stream>>>(x, xb, SEQ * HID / 4);
  // 2. transpose-cast weights into fused [4608][3584]
  transpose_cast_kernel<<<dim3(HID / 64, HID / 64), 256, 0, stream>>>(wq, wT, HID, HID);
  transpose_cast_kernel<<<dim3((NKV * HD) / 64, HID / 64), 256, 0, stream>>>(
      wk, wT + (size_t)(NH * HD) * HID, HID, NKV * HD);
  transpose_cast_kernel<<<dim3((NKV * HD) / 64, HID / 64), 256, 0, stream>>>(
      wv, wT + (size_t)(NH * HD + NKV * HD) * HID, HID, NKV * HD);
  // 3. fused QKV projection
  gemm_mfma<<<dim3(NQKV / 128, SEQ / 128), 256, 0, stream>>>(
      xb, wT, bq, nullptr, qb, kb_, vbT, bk, bv, SEQ, NQKV, HID, 3);
  // 4. RoPE on q, k
  rope_kernel<<<dim3(SEQ, NH), 64, 0, stream>>>(qb, cosd, sind, NH);
  rope_kernel<<<dim3(SEQ, NKV), 64, 0, stream>>>(kb_, cosd, sind, NKV);
  // 5. split-K attention + reduce
  attn_split<<<dim3(NSLOT, NH), 256, 0, stream>>>(qb, kb_, vbT, Opart, Mpart, Lpart);
  attn_reduce<<<dim3(SEQ, NH), 128, 0, stream>>>(Opart, Mpart, Lpart, aob);
  // 6. output projection (reuse wT region for wo^T; partials dead after reduce)
  transpose_cast_kernel<<<dim3(HID / 64, HID / 64), 256, 0, stream>>>(wo, wT, HID, HID);
  gemm_mfma<<<dim3(HID / 128, SEQ / 128), 256, 0, stream>>>(
      aob, wT, nullptr, out, nullptr, nullptr, nullptr, nullptr, nullptr, SEQ, HID, HID, 0);
}